// Round 8
// baseline (373.270 us; speedup 1.0000x reference)
//
#include <hip/hip_runtime.h>
#include <math.h>

#define BN 16
#define SN 8192
#define DN 256
#define MBLK 256
#define EPSF 1e-8f

#define CHUNK_B 16384            // one W chunk: 16 cols x (q,k) frag-major
#define NCHUNK 17                // 16 W chunks + 1 gate chunk (8KB used)
#define BIAS_OFF 65536           // f32[512]: bq 0..255, bk 256..511
#define KB_OFF   (65536 + 2048)  // f32[256]: block-boundary k row
#define KX_OFF   (65536 + 3072)  // f32[2][4][16]: cross-wave k exchange
#define LDS_BYTES (65536 + 3072 + 512)   // 69120

typedef __attribute__((ext_vector_type(8))) short short8;
typedef __attribute__((ext_vector_type(4))) float f32x4;

typedef const __attribute__((address_space(1))) unsigned int g_u32;
typedef __attribute__((address_space(3))) unsigned int l_u32;

__device__ __forceinline__ unsigned short f2bf(float f) {
    union { float f; unsigned int u; } cv; cv.f = f;
    unsigned int u = cv.u + 0x7FFFu + ((cv.u >> 16) & 1u);
    return (unsigned short)(u >> 16);
}

__device__ __forceinline__ void gload_lds16(const void* g, void* l) {
    __builtin_amdgcn_global_load_lds((g_u32*)g, (l_u32*)l, 16, 0, 0);
}

// ---------------------------------------------------------------------------
// k0: rewrite Wq/Wk into frag-major bf16 layout, 16 chunks x 16KB, plus the
// gate chunk (index 16, first 8KB): ds_read_b128 of a frag = base + lane*16.
// ---------------------------------------------------------------------------
__global__ void k0_prep(const float* __restrict__ Wq, const float* __restrict__ Wk,
                        const float* __restrict__ w_vol, const float* __restrict__ w_volu,
                        unsigned char* __restrict__ Wfrag)
{
    const int tid = threadIdx.x;
    const int n   = blockIdx.x * 8 + (tid >> 5);   // 0..255
    const int k8  = tid & 31;                      // 8-elem group of K
    const int ch  = n >> 4;
    const int cc  = n & 15;
    const int ks  = k8 >> 2;
    const int g   = k8 & 3;

    short8 vq, vk;
    #pragma unroll
    for (int e = 0; e < 8; ++e) {
        const int k = k8 * 8 + e;
        vq[e] = (short)f2bf(Wq[(size_t)k * DN + n]);
        vk[e] = (short)f2bf(Wk[(size_t)k * DN + n]);
    }
    const size_t base = (size_t)ch * CHUNK_B + (size_t)((g * 16 + cc) * 16);
    *(short8*)(Wfrag + base + (size_t)(ks)     * 1024) = vq;
    *(short8*)(Wfrag + base + (size_t)(8 + ks) * 1024) = vk;

    unsigned char* Gfrag = Wfrag + (size_t)16 * CHUNK_B;
    if (blockIdx.x < 2) {
        const int gc = blockIdx.x * 8 + (tid >> 5);   // 0..15
        short8 vg;
        #pragma unroll
        for (int e = 0; e < 8; ++e) {
            const int k = k8 * 8 + e;
            float v = (gc == 0) ? w_vol[k] : ((gc == 1) ? w_volu[k] : 0.0f);
            vg[e] = (short)f2bf(v);
        }
        *(short8*)(Gfrag + (size_t)ks * 1024 + (size_t)((g * 16 + gc) * 16)) = vg;
    }
}

// ---------------------------------------------------------------------------
// k0b: k-projection (NO bias) at block-boundary rows s = 255 + 256*j,
// j = 0..31 per batch. kpatch[b][j][n], fp32. 4 rows/block, 8x16 blocks.
// ---------------------------------------------------------------------------
__global__ void k0b_kpatch(const float* __restrict__ x, const float* __restrict__ Wk,
                           float* __restrict__ kpatch)
{
    __shared__ float xr[4][DN];
    const int b  = blockIdx.y;
    const int r0 = blockIdx.x * 4;
    const int t  = threadIdx.x;
    #pragma unroll
    for (int m = 0; m < 4; ++m)
        xr[m][t] = x[((size_t)b * SN + 255 + (size_t)(r0 + m) * 256) * DN + t];
    __syncthreads();
    float acc[4] = {0.f, 0.f, 0.f, 0.f};
    #pragma unroll 4
    for (int k = 0; k < DN; k += 4) {
        const float w0 = Wk[(size_t)k * DN + t];
        const float w1 = Wk[(size_t)(k + 1) * DN + t];
        const float w2 = Wk[(size_t)(k + 2) * DN + t];
        const float w3 = Wk[(size_t)(k + 3) * DN + t];
        #pragma unroll
        for (int m = 0; m < 4; ++m) {
            const float4 xv = *(const float4*)&xr[m][k];
            acc[m] = fmaf(xv.w, w3, fmaf(xv.z, w2, fmaf(xv.y, w1, fmaf(xv.x, w0, acc[m]))));
        }
    }
    #pragma unroll
    for (int m = 0; m < 4; ++m)
        kpatch[((size_t)b * 32 + r0 + m) * DN + t] = acc[m];
}

// ---------------------------------------------------------------------------
// k1: 4 waves x 64 rows (M=4). k_{s-1} via accumulator row-shift in-wave,
// cross-wave via LDS kx exchange (deferred 1 phase), cross-block via kpatch.
// Phase 1: x staged in 64-row quarters; wave j extracts its own quarter.
// Phase 2: 17 chunks through 4 x 16KB buffers, exact counted vmcnt.
// ---------------------------------------------------------------------------
__global__ __launch_bounds__(256, 2) void k1_mfma(
    const float* __restrict__ x,
    const unsigned char* __restrict__ Wfrag,
    const float* __restrict__ kpatch,
    const float* __restrict__ bq, const float* __restrict__ bk,
    const float* __restrict__ b_vol, const float* __restrict__ b_volu,
    float* __restrict__ bp_out, int* __restrict__ flags)
{
    extern __shared__ unsigned char lds[];           // 69120 B

    const int tid  = threadIdx.x;
    const int wq   = tid >> 6;                       // 0..3
    const int l    = tid & 63;
    const int g    = l >> 4;
    const int c    = l & 15;
    const int b    = blockIdx.y;
    const int blkx = blockIdx.x;
    const int s0   = blkx * MBLK;

    float* bias_lds = (float*)(lds + BIAS_OFF);
    float* kb_lds   = (float*)(lds + KB_OFF);
    float* kx_lds   = (float*)(lds + KX_OFF);

    const float* xb = x + (size_t)b * SN * DN;

    // ---- phase 1: stage quarter 0 (64 rows, 32KB) into half 0
    {
        unsigned char* reg = lds;
        #pragma unroll
        for (int it = 0; it < 8; ++it) {
            const int f = it * 256 + tid;            // 0..2047
            const int lr = f >> 5, ch = f & 31;
            const float4* p = (const float4*)(xb + (size_t)(s0 + lr) * DN + ch * 8);
            const float4 aa = p[0], dd = p[1];
            short8 sv;
            sv[0] = (short)f2bf(aa.x); sv[1] = (short)f2bf(aa.y);
            sv[2] = (short)f2bf(aa.z); sv[3] = (short)f2bf(aa.w);
            sv[4] = (short)f2bf(dd.x); sv[5] = (short)f2bf(dd.y);
            sv[6] = (short)f2bf(dd.z); sv[7] = (short)f2bf(dd.w);
            *(short8*)(reg + lr * 512 + ((ch * 16) ^ ((lr & 7) << 4))) = sv;
        }
    }
    __syncthreads();

    short8 a[4][8];
    #pragma unroll
    for (int j = 0; j < 4; ++j) {
        if (j < 3) {
            unsigned char* reg = lds + ((j + 1) & 1) * 32768;
            #pragma unroll
            for (int it = 0; it < 8; ++it) {
                const int f = it * 256 + tid;
                const int lr = f >> 5, ch = f & 31;
                const float4* p = (const float4*)(xb + (size_t)(s0 + (j + 1) * 64 + lr) * DN + ch * 8);
                const float4 aa = p[0], dd = p[1];
                short8 sv;
                sv[0] = (short)f2bf(aa.x); sv[1] = (short)f2bf(aa.y);
                sv[2] = (short)f2bf(aa.z); sv[3] = (short)f2bf(aa.w);
                sv[4] = (short)f2bf(dd.x); sv[5] = (short)f2bf(dd.y);
                sv[6] = (short)f2bf(dd.z); sv[7] = (short)f2bf(dd.w);
                *(short8*)(reg + lr * 512 + ((ch * 16) ^ ((lr & 7) << 4))) = sv;
            }
        }
        if (wq == j) {
            const unsigned char* reg = lds + (j & 1) * 32768;
            #pragma unroll
            for (int m = 0; m < 4; ++m) {
                const int lr = m * 16 + c;
                #pragma unroll
                for (int ks = 0; ks < 8; ++ks)
                    a[m][ks] = *(const short8*)(reg + lr * 512 + (((ks * 64) + g * 16) ^ ((lr & 7) << 4)));
            }
        }
        __syncthreads();
    }

    // ---- small LDS copies: biases + block-boundary k row
    {
        bias_lds[tid]       = bq[tid];
        bias_lds[256 + tid] = bk[tid];
        int j = blkx - 1; if (j < 0) j = 0;         // blkx==0 value unused (s==0 override)
        kb_lds[tid] = kpatch[((size_t)b * 32 + j) * DN + tid];
    }

    // ---- phase 2 prologue: stage chunks 0,1,2
    #pragma unroll
    for (int ch = 0; ch < 3; ++ch)
        #pragma unroll
        for (int j = 0; j < 4; ++j)
            gload_lds16(Wfrag + (size_t)ch * CHUNK_B + j * 4096 + tid * 16,
                        lds + ch * CHUNK_B + j * 4096 + wq * 1024);
    asm volatile("s_waitcnt vmcnt(8) lgkmcnt(0)" ::: "memory");
    __builtin_amdgcn_s_barrier();

    float dt[4][4], nqv[4][4], nkv[4][4];
    #pragma unroll
    for (int m = 0; m < 4; ++m)
        #pragma unroll
        for (int r = 0; r < 4; ++r) { dt[m][r] = 0.f; nqv[m][r] = 0.f; nkv[m][r] = 0.f; }
    f32x4 cg[4];
    #pragma unroll
    for (int m = 0; m < 4; ++m) cg[m] = (f32x4)(0.f);

    float qv0_prev = 0.f, bkc_prev = 0.f;

    // ---- main loop: 17 chunks, 4-buffer, exact counted vmcnt
    #pragma unroll
    for (int i = 0; i < NCHUNK; ++i) {
        // stage chunk i+3
        if (i + 3 < 16) {
            #pragma unroll
            for (int j = 0; j < 4; ++j)
                gload_lds16(Wfrag + (size_t)(i + 3) * CHUNK_B + j * 4096 + tid * 16,
                            lds + ((i + 3) & 3) * CHUNK_B + j * 4096 + wq * 1024);
        } else if (i + 3 == 16) {
            #pragma unroll
            for (int j = 0; j < 2; ++j)
                gload_lds16(Wfrag + (size_t)16 * CHUNK_B + j * 4096 + tid * 16,
                            lds + (16 & 3) * CHUNK_B + j * 4096 + wq * 1024);
        }
        const unsigned char* bb = lds + (i & 3) * CHUNK_B;

        if (i < 16) {
            f32x4 cq[4], ck[4];
            #pragma unroll
            for (int m = 0; m < 4; ++m) { cq[m] = (f32x4)(0.f); ck[m] = (f32x4)(0.f); }
            __builtin_amdgcn_s_setprio(1);
            #pragma unroll
            for (int ks = 0; ks < 8; ++ks) {
                const short8 bqf = *(const short8*)(bb + ks * 1024 + l * 16);
                const short8 bkf = *(const short8*)(bb + (8 + ks) * 1024 + l * 16);
                #pragma unroll
                for (int m = 0; m < 4; ++m) {
                    cq[m] = __builtin_amdgcn_mfma_f32_16x16x32_bf16(a[m][ks], bqf, cq[m], 0, 0, 0);
                    ck[m] = __builtin_amdgcn_mfma_f32_16x16x32_bf16(a[m][ks], bkf, ck[m], 0, 0, 0);
                }
            }
            __builtin_amdgcn_s_setprio(0);

            // deferred consume of chunk i-1's wave-boundary element
            if (i >= 1) {
                float km;
                if (wq == 0) km = kb_lds[(i - 1) * 16 + c];
                else         km = kx_lds[(((i - 1) & 1) * 4 + (wq - 1)) * 16 + c];
                if (g == 0) {
                    const float kv = km + bkc_prev;
                    dt[0][0]  = fmaf(qv0_prev, kv, dt[0][0]);
                    nkv[0][0] = fmaf(kv, kv, nkv[0][0]);
                }
            }

            // publish this wave's last k row (local row 63) for wave wq+1
            if (g == 3) kx_lds[((i & 1) * 4 + wq) * 16 + c] = ck[3][3];

            // fold
            const float bqc = bias_lds[i * 16 + c];
            const float bkc = bias_lds[256 + i * 16 + c];
            float sh[4], cr[4];
            #pragma unroll
            for (int m = 0; m < 4; ++m) sh[m] = __shfl(ck[m][3], (l - 16) & 63);
            cr[0] = 0.f;
            #pragma unroll
            for (int m = 1; m < 4; ++m) cr[m] = __shfl(ck[m - 1][3], 48 + c);

            #pragma unroll
            for (int m = 0; m < 4; ++m)
                #pragma unroll
                for (int r = 0; r < 4; ++r) {
                    const float qv = cq[m][r] + bqc;
                    nqv[m][r] = fmaf(qv, qv, nqv[m][r]);
                    float kraw;
                    if (r > 0)      kraw = ck[m][r - 1];
                    else if (m == 0) kraw = sh[0];
                    else             kraw = (g == 0) ? cr[m] : sh[m];
                    if (m == 0 && r == 0) {
                        if (g == 0) { qv0_prev = qv; bkc_prev = bkc; }
                        else {
                            const float kv = kraw + bkc;
                            dt[0][0]  = fmaf(qv, kv, dt[0][0]);
                            nkv[0][0] = fmaf(kv, kv, nkv[0][0]);
                        }
                    } else {
                        const float kv = kraw + bkc;
                        dt[m][r]  = fmaf(qv, kv, dt[m][r]);
                        nkv[m][r] = fmaf(kv, kv, nkv[m][r]);
                    }
                }
        } else {
            // gate chunk (q-side only) + final deferred consume (chunk 15)
            __builtin_amdgcn_s_setprio(1);
            #pragma unroll
            for (int ks = 0; ks < 8; ++ks) {
                const short8 bgf = *(const short8*)(bb + ks * 1024 + l * 16);
                #pragma unroll
                for (int m = 0; m < 4; ++m)
                    cg[m] = __builtin_amdgcn_mfma_f32_16x16x32_bf16(a[m][ks], bgf, cg[m], 0, 0, 0);
            }
            __builtin_amdgcn_s_setprio(0);
            float km;
            if (wq == 0) km = kb_lds[15 * 16 + c];
            else         km = kx_lds[((15 & 1) * 4 + (wq - 1)) * 16 + c];
            if (g == 0) {
                const float kv = km + bkc_prev;
                dt[0][0]  = fmaf(qv0_prev, kv, dt[0][0]);
                nkv[0][0] = fmaf(kv, kv, nkv[0][0]);
            }
        }

        // exact counted waits (staging loads are the ONLY vmem in this loop)
        if (i < 16) {
            if (i <= 12)      asm volatile("s_waitcnt vmcnt(8) lgkmcnt(0)" ::: "memory");
            else if (i == 13) asm volatile("s_waitcnt vmcnt(6) lgkmcnt(0)" ::: "memory");
            else if (i == 14) asm volatile("s_waitcnt vmcnt(2) lgkmcnt(0)" ::: "memory");
            else              asm volatile("s_waitcnt vmcnt(0) lgkmcnt(0)" ::: "memory");
            __builtin_amdgcn_s_barrier();
        }
    }

    // ---- reduce over the 16 col-lanes of each group
    #pragma unroll
    for (int m = 0; m < 4; ++m)
        #pragma unroll
        for (int r = 0; r < 4; ++r) {
            float aa = dt[m][r], e = nqv[m][r], f = nkv[m][r];
            #pragma unroll
            for (int mask = 1; mask < 16; mask <<= 1) {
                aa += __shfl_xor(aa, mask);
                e  += __shfl_xor(e, mask);
                f  += __shfl_xor(f, mask);
            }
            dt[m][r] = aa; nqv[m][r] = e; nkv[m][r] = f;
        }
    float vu[4][4];
    #pragma unroll
    for (int m = 0; m < 4; ++m)
        #pragma unroll
        for (int r = 0; r < 4; ++r) vu[m][r] = __shfl_xor(cg[m][r], 1);

    if (c == 0) {
        const float bv = b_vol[0], bu = b_volu[0];
        #pragma unroll
        for (int m = 0; m < 4; ++m)
            #pragma unroll
            for (int r = 0; r < 4; ++r) {
                const int s = s0 + wq * 64 + m * 16 + g * 4 + r;
                float comb;
                if (s == 0) comb = 1.0f;
                else {
                    float denom = fmaxf(sqrtf(nqv[m][r]), EPSF) * fmaxf(sqrtf(nkv[m][r]), EPSF);
                    float sim   = dt[m][r] / denom;
                    float vol   = 1.f / (1.f + expf(-(cg[m][r] + bv)));
                    float volu  = 1.f / (1.f + expf(-(vu[m][r] + bu)));
                    comb = (1.f - sim) + 0.3f * vol + 0.2f * volu;
                }
                const float pbp = 1.f / (1.f + expf(-comb));
                const size_t o = (size_t)b * SN + s;
                bp_out[o] = pbp;
                flags[o]  = (pbp > 0.5f) ? 1 : 0;
            }
    }
}

// ---------------------------------------------------------------------------
// k2: per-batch scan of hard flags -> packed dest index, count, boundary sum
// ---------------------------------------------------------------------------
__global__ void k2_scan(const int* __restrict__ flags,
                        const float* __restrict__ bp,
                        int* __restrict__ pidx,
                        int* __restrict__ cnt,
                        float* __restrict__ bsum)
{
    const int b = blockIdx.x;
    const int t = threadIdx.x;
    __shared__ int   ssum[256];
    __shared__ float sf[256];

    const size_t base = (size_t)b * SN + (size_t)t * 32;
    int f[32];
    int run = 0;
    float fs = 0.f;
    #pragma unroll
    for (int i = 0; i < 32; ++i) {
        f[i] = flags[base + i];
        run += f[i];
        float p  = bp[base + i];
        float hf = (float)f[i];
        fs += hf + p - p;
    }
    ssum[t] = run;
    sf[t]   = fs;
    __syncthreads();

    for (int off = 1; off < 256; off <<= 1) {
        int v = (t >= off) ? ssum[t - off] : 0;
        __syncthreads();
        ssum[t] += v;
        __syncthreads();
    }
    const int incl = ssum[t];
    int running = incl - run;
    #pragma unroll
    for (int i = 0; i < 32; ++i) {
        running += f[i];
        pidx[base + i] = f[i] ? (running - 1) : -1;
    }
    if (t == 255) cnt[b] = incl;

    for (int off = 128; off > 0; off >>= 1) {
        if (t < off) sf[t] += sf[t + off];
        __syncthreads();
    }
    if (t == 0) bsum[b] = sf[0];
}

// ---------------------------------------------------------------------------
// k3: gather-copy hard rows; 4 rows per 256-thread block
// ---------------------------------------------------------------------------
__global__ void k3_scatter(const float* __restrict__ x,
                           const int* __restrict__ pidx,
                           float* __restrict__ out_comp)
{
    const int row  = blockIdx.x * 4 + (threadIdx.x >> 6);
    const int lane = threadIdx.x & 63;
    const int p = pidx[row];
    if (p < 0) return;
    const int b = row >> 13;
    const float4* src = (const float4*)(x + (size_t)row * DN);
    float4* dst = (float4*)(out_comp + ((size_t)b * SN + p) * DN);
    dst[lane] = src[lane];
}

// k3b: zero destination rows beyond each batch's boundary count
__global__ void k3b_zerotail(float* __restrict__ out_comp,
                             const int* __restrict__ cnt)
{
    const int gid = blockIdx.x * blockDim.x + threadIdx.x;
    const int b = gid >> 13;
    const int j = gid & (SN - 1);
    if (j >= cnt[b]) {
        float4* dst = (float4*)(out_comp + ((size_t)b * SN + j) * DN);
        const float4 z = make_float4(0.f, 0.f, 0.f, 0.f);
        for (int i = 0; i < DN / 4; ++i) dst[i] = z;
    }
}

// k4: ratio loss
__global__ void k4_loss(const float* __restrict__ bsum, float* __restrict__ out_rl)
{
    if (threadIdx.x == 0) {
        float acc = 0.f;
        for (int i = 0; i < BN; ++i) acc += bsum[i];
        float mean = acc / (float)BN;
        float d = mean - (float)(SN / 4);
        out_rl[0] = d * d;
    }
}

extern "C" void kernel_launch(void* const* d_in, const int* in_sizes, int n_in,
                              void* d_out, int out_size, void* d_ws, size_t ws_size,
                              hipStream_t stream) {
    const float* x      = (const float*)d_in[0];
    const float* Wq     = (const float*)d_in[1];
    const float* bq     = (const float*)d_in[2];
    const float* Wk     = (const float*)d_in[3];
    const float* bk     = (const float*)d_in[4];
    const float* w_vol  = (const float*)d_in[5];
    const float* b_vol  = (const float*)d_in[6];
    const float* w_volu = (const float*)d_in[7];
    const float* b_volu = (const float*)d_in[8];

    float* out_comp = (float*)d_out;                       // B*S*D
    float* out_bp   = out_comp + (size_t)BN * SN * DN;     // B*S
    float* out_rl   = out_bp + (size_t)BN * SN;            // 1

    int*   flags = (int*)d_ws;                             // B*S
    int*   pidx  = flags + (size_t)BN * SN;                // B*S
    int*   cnt   = pidx + (size_t)BN * SN;                 // B
    float* bsum  = (float*)(cnt + BN);                     // B
    unsigned char* Wfrag = (unsigned char*)(bsum + BN);    // 17*16384 = 278528 B
    float* kpatch = (float*)(Wfrag + (size_t)NCHUNK * CHUNK_B); // 16*32*256 f32

    k0_prep<<<32, 256, 0, stream>>>(Wq, Wk, w_vol, w_volu, Wfrag);

    k0b_kpatch<<<dim3(8, BN), 256, 0, stream>>>(x, Wk, kpatch);

    hipFuncSetAttribute((const void*)k1_mfma,
                        hipFuncAttributeMaxDynamicSharedMemorySize, LDS_BYTES);

    k1_mfma<<<dim3(SN / MBLK, BN), 256, LDS_BYTES, stream>>>(
        x, Wfrag, kpatch, bq, bk, b_vol, b_volu, out_bp, flags);

    k2_scan<<<BN, 256, 0, stream>>>(flags, out_bp, pidx, cnt, bsum);

    k3_scatter<<<(BN * SN) / 4, 256, 0, stream>>>(x, pidx, out_comp);

    k3b_zerotail<<<(BN * SN) / 256, 256, 0, stream>>>(out_comp, cnt);

    k4_loss<<<1, 64, 0, stream>>>(bsum, out_rl);
}

// Round 9
// 322.320 us; speedup vs baseline: 1.1581x; 1.1581x over previous
//
#include <hip/hip_runtime.h>
#include <math.h>

#define BN 16
#define SN 8192
#define DN 256
#define MBLK 256
#define EPSF 1e-8f

#define CHUNK_B 16384            // one W chunk: 16 cols x (q,k) frag-major
#define NCHUNK 17                // 16 W chunks + 1 gate chunk (8KB used)
#define BIAS_OFF 65536           // f32[512]: bq 0..255, bk 256..511
#define KB_OFF   (65536 + 2048)  // f32[256]: block-boundary k row (s0-1)
#define KX_OFF   (65536 + 3072)  // f32[2][8][16]: cross-wave k exchange
#define LDS_BYTES (65536 + 3072 + 1024)   // 69632

typedef __attribute__((ext_vector_type(8))) short short8;
typedef __attribute__((ext_vector_type(4))) float f32x4;

typedef const __attribute__((address_space(1))) unsigned int g_u32;
typedef __attribute__((address_space(3))) unsigned int l_u32;

__device__ __forceinline__ unsigned short f2bf(float f) {
    union { float f; unsigned int u; } cv; cv.f = f;
    unsigned int u = cv.u + 0x7FFFu + ((cv.u >> 16) & 1u);
    return (unsigned short)(u >> 16);
}

__device__ __forceinline__ void gload_lds16(const void* g, void* l) {
    __builtin_amdgcn_global_load_lds((g_u32*)g, (l_u32*)l, 16, 0, 0);
}

// ---------------------------------------------------------------------------
// k0: rewrite Wq/Wk into frag-major bf16 layout, 16 chunks x 16KB, plus the
// gate chunk (index 16, first 8KB): ds_read_b128 of a frag = base + lane*16.
// ---------------------------------------------------------------------------
__global__ void k0_prep(const float* __restrict__ Wq, const float* __restrict__ Wk,
                        const float* __restrict__ w_vol, const float* __restrict__ w_volu,
                        unsigned char* __restrict__ Wfrag)
{
    const int tid = threadIdx.x;
    const int n   = blockIdx.x * 8 + (tid >> 5);   // 0..255
    const int k8  = tid & 31;                      // 8-elem group of K
    const int ch  = n >> 4;
    const int cc  = n & 15;
    const int ks  = k8 >> 2;
    const int g   = k8 & 3;

    short8 vq, vk;
    #pragma unroll
    for (int e = 0; e < 8; ++e) {
        const int k = k8 * 8 + e;
        vq[e] = (short)f2bf(Wq[(size_t)k * DN + n]);
        vk[e] = (short)f2bf(Wk[(size_t)k * DN + n]);
    }
    const size_t base = (size_t)ch * CHUNK_B + (size_t)((g * 16 + cc) * 16);
    *(short8*)(Wfrag + base + (size_t)(ks)     * 1024) = vq;
    *(short8*)(Wfrag + base + (size_t)(8 + ks) * 1024) = vk;

    unsigned char* Gfrag = Wfrag + (size_t)16 * CHUNK_B;
    if (blockIdx.x < 2) {
        const int gc = blockIdx.x * 8 + (tid >> 5);   // 0..15
        short8 vg;
        #pragma unroll
        for (int e = 0; e < 8; ++e) {
            const int k = k8 * 8 + e;
            float v = (gc == 0) ? w_vol[k] : ((gc == 1) ? w_volu[k] : 0.0f);
            vg[e] = (short)f2bf(v);
        }
        *(short8*)(Gfrag + (size_t)ks * 1024 + (size_t)((g * 16 + gc) * 16)) = vg;
    }
}

// ---------------------------------------------------------------------------
// k0b: k-projection (NO bias) at block-boundary rows s = 255 + 256*j,
// j = 0..31 per batch. kpatch[b][j][n], fp32. 8 rows/block, 4x16 blocks.
// ---------------------------------------------------------------------------
__global__ void k0b_kpatch(const float* __restrict__ x, const float* __restrict__ Wk,
                           float* __restrict__ kpatch)
{
    __shared__ float xr[8][DN];
    const int b  = blockIdx.y;
    const int r0 = blockIdx.x * 8;
    const int t  = threadIdx.x;
    #pragma unroll
    for (int m = 0; m < 8; ++m)
        xr[m][t] = x[((size_t)b * SN + 255 + (size_t)(r0 + m) * 256) * DN + t];
    __syncthreads();
    float acc[8] = {0.f, 0.f, 0.f, 0.f, 0.f, 0.f, 0.f, 0.f};
    #pragma unroll 2
    for (int k = 0; k < DN; k += 4) {
        const float w0 = Wk[(size_t)k * DN + t];
        const float w1 = Wk[(size_t)(k + 1) * DN + t];
        const float w2 = Wk[(size_t)(k + 2) * DN + t];
        const float w3 = Wk[(size_t)(k + 3) * DN + t];
        #pragma unroll
        for (int m = 0; m < 8; ++m) {
            const float4 xv = *(const float4*)&xr[m][k];
            acc[m] = fmaf(xv.w, w3, fmaf(xv.z, w2, fmaf(xv.y, w1, fmaf(xv.x, w0, acc[m]))));
        }
    }
    #pragma unroll
    for (int m = 0; m < 8; ++m)
        kpatch[((size_t)b * 32 + r0 + m) * DN + t] = acc[m];
}

// ---------------------------------------------------------------------------
// k1: 8 waves x 32 rows (M=2), 256 rows/block. k_{s-1} via in-wave accumulator
// row-shift; cross-wave boundary via deferred LDS kx exchange; cross-block via
// kpatch (kb_lds). Phase 1: x staged in 64-row quarters ping-ponging LDS
// halves. Phase 2: 17 chunks through 4 x 16KB buffers, exact counted vmcnt.
// ---------------------------------------------------------------------------
__global__ __launch_bounds__(512, 4) void k1_mfma(
    const float* __restrict__ x,
    const unsigned char* __restrict__ Wfrag,
    const float* __restrict__ kpatch,
    const float* __restrict__ bq, const float* __restrict__ bk,
    const float* __restrict__ b_vol, const float* __restrict__ b_volu,
    float* __restrict__ bp_out, int* __restrict__ flags)
{
    extern __shared__ unsigned char lds[];           // 69632 B

    const int tid  = threadIdx.x;
    const int wq   = tid >> 6;                       // 0..7
    const int l    = tid & 63;
    const int g    = l >> 4;
    const int c    = l & 15;
    const int b    = blockIdx.y;
    const int blkx = blockIdx.x;
    const int s0   = blkx * MBLK;

    float* bias_lds = (float*)(lds + BIAS_OFF);
    float* kb_lds   = (float*)(lds + KB_OFF);
    float* kx_lds   = (float*)(lds + KX_OFF);

    const float* xb = x + (size_t)b * SN * DN;

    // ---- phase 1: quarter j (64 rows, 32KB) lives in LDS half j&1
    short8 a[2][8];
    {
        {
            unsigned char* reg = lds;
            #pragma unroll
            for (int it = 0; it < 4; ++it) {
                const int f = it * 512 + tid;            // 0..2047
                const int lr = f >> 5, ch = f & 31;      // 64 rows x 32 chunks
                const float4* p = (const float4*)(xb + (size_t)(s0 + lr) * DN + ch * 8);
                const float4 aa = p[0], dd = p[1];
                short8 sv;
                sv[0] = (short)f2bf(aa.x); sv[1] = (short)f2bf(aa.y);
                sv[2] = (short)f2bf(aa.z); sv[3] = (short)f2bf(aa.w);
                sv[4] = (short)f2bf(dd.x); sv[5] = (short)f2bf(dd.y);
                sv[6] = (short)f2bf(dd.z); sv[7] = (short)f2bf(dd.w);
                *(short8*)(reg + lr * 512 + ((ch * 16) ^ ((lr & 7) << 4))) = sv;
            }
        }
        __syncthreads();
        #pragma unroll
        for (int j = 0; j < 4; ++j) {
            if (j < 3) {
                unsigned char* reg = lds + ((j + 1) & 1) * 32768;
                #pragma unroll
                for (int it = 0; it < 4; ++it) {
                    const int f = it * 512 + tid;
                    const int lr = f >> 5, ch = f & 31;
                    const float4* p = (const float4*)(xb + (size_t)(s0 + (j + 1) * 64 + lr) * DN + ch * 8);
                    const float4 aa = p[0], dd = p[1];
                    short8 sv;
                    sv[0] = (short)f2bf(aa.x); sv[1] = (short)f2bf(aa.y);
                    sv[2] = (short)f2bf(aa.z); sv[3] = (short)f2bf(aa.w);
                    sv[4] = (short)f2bf(dd.x); sv[5] = (short)f2bf(dd.y);
                    sv[6] = (short)f2bf(dd.z); sv[7] = (short)f2bf(dd.w);
                    *(short8*)(reg + lr * 512 + ((ch * 16) ^ ((lr & 7) << 4))) = sv;
                }
            }
            if ((wq >> 1) == j) {
                const unsigned char* reg = lds + (j & 1) * 32768;
                #pragma unroll
                for (int m = 0; m < 2; ++m) {
                    const int lr = (wq & 1) * 32 + m * 16 + c;
                    #pragma unroll
                    for (int ks = 0; ks < 8; ++ks)
                        a[m][ks] = *(const short8*)(reg + lr * 512 + (((ks * 64) + g * 16) ^ ((lr & 7) << 4)));
                }
            }
            __syncthreads();
        }
    }

    // ---- small LDS copies: biases + block-boundary k row
    if (tid < 256) {
        bias_lds[tid]       = bq[tid];
        bias_lds[256 + tid] = bk[tid];
        int j = blkx - 1; if (j < 0) j = 0;          // blkx==0 value unused (s==0 override)
        kb_lds[tid] = kpatch[((size_t)b * 32 + j) * DN + tid];
    }

    // ---- phase 2 prologue: stage chunks 0,1,2 (2 loads/thread each)
    #pragma unroll
    for (int ch = 0; ch < 3; ++ch)
        #pragma unroll
        for (int jj = 0; jj < 2; ++jj)
            gload_lds16(Wfrag + (size_t)ch * CHUNK_B + jj * 8192 + tid * 16,
                        lds + ch * CHUNK_B + jj * 8192 + wq * 1024);
    asm volatile("s_waitcnt vmcnt(4) lgkmcnt(0)" ::: "memory");
    __builtin_amdgcn_s_barrier();

    float dt[2][4], nqv[2][4], nkv[2][4];
    #pragma unroll
    for (int m = 0; m < 2; ++m)
        #pragma unroll
        for (int r = 0; r < 4; ++r) { dt[m][r] = 0.f; nqv[m][r] = 0.f; nkv[m][r] = 0.f; }
    f32x4 cg0 = (f32x4)(0.f), cg1 = (f32x4)(0.f);

    float qv0_prev = 0.f, bkc_prev = 0.f;

    // ---- main loop: 17 chunks, 4-buffer, exact counted vmcnt
    #pragma unroll
    for (int i = 0; i < NCHUNK; ++i) {
        if (i + 3 < 16) {
            #pragma unroll
            for (int jj = 0; jj < 2; ++jj)
                gload_lds16(Wfrag + (size_t)(i + 3) * CHUNK_B + jj * 8192 + tid * 16,
                            lds + ((i + 3) & 3) * CHUNK_B + jj * 8192 + wq * 1024);
        } else if (i + 3 == 16) {
            gload_lds16(Wfrag + (size_t)16 * CHUNK_B + tid * 16,
                        lds + (16 & 3) * CHUNK_B + wq * 1024);
        }
        const unsigned char* bb = lds + (i & 3) * CHUNK_B;

        if (i < 16) {
            f32x4 cq0 = (f32x4)(0.f), cq1 = (f32x4)(0.f);
            f32x4 ck0 = (f32x4)(0.f), ck1 = (f32x4)(0.f);
            __builtin_amdgcn_s_setprio(1);
            #pragma unroll
            for (int ks = 0; ks < 8; ++ks) {
                const short8 bqf = *(const short8*)(bb + ks * 1024 + l * 16);
                const short8 bkf = *(const short8*)(bb + (8 + ks) * 1024 + l * 16);
                cq0 = __builtin_amdgcn_mfma_f32_16x16x32_bf16(a[0][ks], bqf, cq0, 0, 0, 0);
                cq1 = __builtin_amdgcn_mfma_f32_16x16x32_bf16(a[1][ks], bqf, cq1, 0, 0, 0);
                ck0 = __builtin_amdgcn_mfma_f32_16x16x32_bf16(a[0][ks], bkf, ck0, 0, 0, 0);
                ck1 = __builtin_amdgcn_mfma_f32_16x16x32_bf16(a[1][ks], bkf, ck1, 0, 0, 0);
            }
            __builtin_amdgcn_s_setprio(0);

            // deferred consume of chunk i-1's wave-boundary element
            if (i >= 1) {
                float km;
                if (wq == 0) km = kb_lds[(i - 1) * 16 + c];
                else         km = kx_lds[(((i - 1) & 1) * 8 + (wq - 1)) * 16 + c];
                if (g == 0) {
                    const float kv = km + bkc_prev;
                    dt[0][0]  = fmaf(qv0_prev, kv, dt[0][0]);
                    nkv[0][0] = fmaf(kv, kv, nkv[0][0]);
                }
            }
            // publish this wave's last k row (local row 31) for wave wq+1
            if (g == 3) kx_lds[((i & 1) * 8 + wq) * 16 + c] = ck1[3];

            // fold
            const float bqc = bias_lds[i * 16 + c];
            const float bkc = bias_lds[256 + i * 16 + c];
            const float sh0 = __shfl(ck0[3], (l - 16) & 63);   // (g-1, r=3) -> (g, r=0)
            const float sh1 = __shfl(ck1[3], (l - 16) & 63);
            const float cr  = __shfl(ck0[3], 48 + c);          // m0 row15 -> m1 g0 r0
            const float km10 = (g == 0) ? cr : sh1;
            const float kv0[4] = {sh0, ck0[0], ck0[1], ck0[2]};
            const float kv1[4] = {km10, ck1[0], ck1[1], ck1[2]};
            #pragma unroll
            for (int r = 0; r < 4; ++r) {
                float qv = cq0[r] + bqc;
                nqv[0][r] = fmaf(qv, qv, nqv[0][r]);
                if (r == 0) {
                    if (g == 0) { qv0_prev = qv; bkc_prev = bkc; }
                    else {
                        const float kv = kv0[0] + bkc;
                        dt[0][0]  = fmaf(qv, kv, dt[0][0]);
                        nkv[0][0] = fmaf(kv, kv, nkv[0][0]);
                    }
                } else {
                    const float kv = kv0[r] + bkc;
                    dt[0][r]  = fmaf(qv, kv, dt[0][r]);
                    nkv[0][r] = fmaf(kv, kv, nkv[0][r]);
                }
                qv = cq1[r] + bqc;
                nqv[1][r] = fmaf(qv, qv, nqv[1][r]);
                const float kv = kv1[r] + bkc;
                dt[1][r]  = fmaf(qv, kv, dt[1][r]);
                nkv[1][r] = fmaf(kv, kv, nkv[1][r]);
            }
        } else {
            // gate chunk (q-side only) + final deferred consume (chunk 15)
            __builtin_amdgcn_s_setprio(1);
            #pragma unroll
            for (int ks = 0; ks < 8; ++ks) {
                const short8 bgf = *(const short8*)(bb + ks * 1024 + l * 16);
                cg0 = __builtin_amdgcn_mfma_f32_16x16x32_bf16(a[0][ks], bgf, cg0, 0, 0, 0);
                cg1 = __builtin_amdgcn_mfma_f32_16x16x32_bf16(a[1][ks], bgf, cg1, 0, 0, 0);
            }
            __builtin_amdgcn_s_setprio(0);
            float km;
            if (wq == 0) km = kb_lds[15 * 16 + c];
            else         km = kx_lds[((15 & 1) * 8 + (wq - 1)) * 16 + c];
            if (g == 0) {
                const float kv = km + bkc_prev;
                dt[0][0]  = fmaf(qv0_prev, kv, dt[0][0]);
                nkv[0][0] = fmaf(kv, kv, nkv[0][0]);
            }
        }

        // exact counted waits (staging loads are the ONLY vmem in this loop)
        if (i <= 12)      { asm volatile("s_waitcnt vmcnt(4) lgkmcnt(0)" ::: "memory"); __builtin_amdgcn_s_barrier(); }
        else if (i == 13) { asm volatile("s_waitcnt vmcnt(3) lgkmcnt(0)" ::: "memory"); __builtin_amdgcn_s_barrier(); }
        else if (i == 14) { asm volatile("s_waitcnt vmcnt(1) lgkmcnt(0)" ::: "memory"); __builtin_amdgcn_s_barrier(); }
        else if (i == 15) { asm volatile("s_waitcnt vmcnt(0) lgkmcnt(0)" ::: "memory"); __builtin_amdgcn_s_barrier(); }
    }

    // ---- reduce over the 16 col-lanes of each group
    #pragma unroll
    for (int m = 0; m < 2; ++m)
        #pragma unroll
        for (int r = 0; r < 4; ++r) {
            float aa = dt[m][r], e = nqv[m][r], f = nkv[m][r];
            #pragma unroll
            for (int mask = 1; mask < 16; mask <<= 1) {
                aa += __shfl_xor(aa, mask);
                e  += __shfl_xor(e, mask);
                f  += __shfl_xor(f, mask);
            }
            dt[m][r] = aa; nqv[m][r] = e; nkv[m][r] = f;
        }
    float vu0[4], vu1[4];
    #pragma unroll
    for (int r = 0; r < 4; ++r) { vu0[r] = __shfl_xor(cg0[r], 1); vu1[r] = __shfl_xor(cg1[r], 1); }

    if (c == 0) {
        const float bv = b_vol[0], bu = b_volu[0];
        #pragma unroll
        for (int m = 0; m < 2; ++m)
            #pragma unroll
            for (int r = 0; r < 4; ++r) {
                const int s = s0 + wq * 32 + m * 16 + g * 4 + r;
                const float cgv = (m == 0) ? cg0[r] : cg1[r];
                const float vuv = (m == 0) ? vu0[r] : vu1[r];
                float comb;
                if (s == 0) comb = 1.0f;
                else {
                    float denom = fmaxf(sqrtf(nqv[m][r]), EPSF) * fmaxf(sqrtf(nkv[m][r]), EPSF);
                    float sim   = dt[m][r] / denom;
                    float vol   = 1.f / (1.f + expf(-(cgv + bv)));
                    float volu  = 1.f / (1.f + expf(-(vuv + bu)));
                    comb = (1.f - sim) + 0.3f * vol + 0.2f * volu;
                }
                const float pbp = 1.f / (1.f + expf(-comb));
                const size_t o = (size_t)b * SN + s;
                bp_out[o] = pbp;
                flags[o]  = (pbp > 0.5f) ? 1 : 0;
            }
    }
}

// ---------------------------------------------------------------------------
// k2: per-batch scan of hard flags -> packed dest index, count, boundary sum
// ---------------------------------------------------------------------------
__global__ void k2_scan(const int* __restrict__ flags,
                        const float* __restrict__ bp,
                        int* __restrict__ pidx,
                        int* __restrict__ cnt,
                        float* __restrict__ bsum)
{
    const int b = blockIdx.x;
    const int t = threadIdx.x;
    __shared__ int   ssum[256];
    __shared__ float sf[256];

    const size_t base = (size_t)b * SN + (size_t)t * 32;
    int f[32];
    int run = 0;
    float fs = 0.f;
    #pragma unroll
    for (int i = 0; i < 32; ++i) {
        f[i] = flags[base + i];
        run += f[i];
        float p  = bp[base + i];
        float hf = (float)f[i];
        fs += hf + p - p;
    }
    ssum[t] = run;
    sf[t]   = fs;
    __syncthreads();

    for (int off = 1; off < 256; off <<= 1) {
        int v = (t >= off) ? ssum[t - off] : 0;
        __syncthreads();
        ssum[t] += v;
        __syncthreads();
    }
    const int incl = ssum[t];
    int running = incl - run;
    #pragma unroll
    for (int i = 0; i < 32; ++i) {
        running += f[i];
        pidx[base + i] = f[i] ? (running - 1) : -1;
    }
    if (t == 255) cnt[b] = incl;

    for (int off = 128; off > 0; off >>= 1) {
        if (t < off) sf[t] += sf[t + off];
        __syncthreads();
    }
    if (t == 0) bsum[b] = sf[0];
}

// ---------------------------------------------------------------------------
// k3: gather-copy hard rows; 4 rows per 256-thread block
// ---------------------------------------------------------------------------
__global__ void k3_scatter(const float* __restrict__ x,
                           const int* __restrict__ pidx,
                           float* __restrict__ out_comp)
{
    const int row  = blockIdx.x * 4 + (threadIdx.x >> 6);
    const int lane = threadIdx.x & 63;
    const int p = pidx[row];
    if (p < 0) return;
    const int b = row >> 13;
    const float4* src = (const float4*)(x + (size_t)row * DN);
    float4* dst = (float4*)(out_comp + ((size_t)b * SN + p) * DN);
    dst[lane] = src[lane];
}

// k3b: zero destination rows beyond each batch's boundary count
__global__ void k3b_zerotail(float* __restrict__ out_comp,
                             const int* __restrict__ cnt)
{
    const int gid = blockIdx.x * blockDim.x + threadIdx.x;
    const int b = gid >> 13;
    const int j = gid & (SN - 1);
    if (j >= cnt[b]) {
        float4* dst = (float4*)(out_comp + ((size_t)b * SN + j) * DN);
        const float4 z = make_float4(0.f, 0.f, 0.f, 0.f);
        for (int i = 0; i < DN / 4; ++i) dst[i] = z;
    }
}

// k4: ratio loss
__global__ void k4_loss(const float* __restrict__ bsum, float* __restrict__ out_rl)
{
    if (threadIdx.x == 0) {
        float acc = 0.f;
        for (int i = 0; i < BN; ++i) acc += bsum[i];
        float mean = acc / (float)BN;
        float d = mean - (float)(SN / 4);
        out_rl[0] = d * d;
    }
}

extern "C" void kernel_launch(void* const* d_in, const int* in_sizes, int n_in,
                              void* d_out, int out_size, void* d_ws, size_t ws_size,
                              hipStream_t stream) {
    const float* x      = (const float*)d_in[0];
    const float* Wq     = (const float*)d_in[1];
    const float* bq     = (const float*)d_in[2];
    const float* Wk     = (const float*)d_in[3];
    const float* bk     = (const float*)d_in[4];
    const float* w_vol  = (const float*)d_in[5];
    const float* b_vol  = (const float*)d_in[6];
    const float* w_volu = (const float*)d_in[7];
    const float* b_volu = (const float*)d_in[8];

    float* out_comp = (float*)d_out;                       // B*S*D
    float* out_bp   = out_comp + (size_t)BN * SN * DN;     // B*S
    float* out_rl   = out_bp + (size_t)BN * SN;            // 1

    int*   flags = (int*)d_ws;                             // B*S
    int*   pidx  = flags + (size_t)BN * SN;                // B*S
    int*   cnt   = pidx + (size_t)BN * SN;                 // B
    float* bsum  = (float*)(cnt + BN);                     // B
    unsigned char* Wfrag = (unsigned char*)(bsum + BN);    // 17*16384 = 278528 B
    float* kpatch = (float*)(Wfrag + (size_t)NCHUNK * CHUNK_B); // 16*32*256 f32

    k0_prep<<<32, 256, 0, stream>>>(Wq, Wk, w_vol, w_volu, Wfrag);

    k0b_kpatch<<<dim3(4, BN), 256, 0, stream>>>(x, Wk, kpatch);

    hipFuncSetAttribute((const void*)k1_mfma,
                        hipFuncAttributeMaxDynamicSharedMemorySize, LDS_BYTES);

    k1_mfma<<<dim3(SN / MBLK, BN), 512, LDS_BYTES, stream>>>(
        x, Wfrag, kpatch, bq, bk, b_vol, b_volu, out_bp, flags);

    k2_scan<<<BN, 256, 0, stream>>>(flags, out_bp, pidx, cnt, bsum);

    k3_scatter<<<(BN * SN) / 4, 256, 0, stream>>>(x, pidx, out_comp);

    k3b_zerotail<<<(BN * SN) / 256, 256, 0, stream>>>(out_comp, cnt);

    k4_loss<<<1, 64, 0, stream>>>(bsum, out_rl);
}

// Round 10
// 145.968 us; speedup vs baseline: 2.5572x; 2.2082x over previous
//
#include <hip/hip_runtime.h>
#include <math.h>

#define BN 16
#define SN 8192
#define DN 256
#define MBLK 256
#define EPSF 1e-8f

#define CHUNK_B 16384            // one W chunk: 16 cols x (q,k) frag-major
#define NCHUNK 17                // 16 W chunks + 1 gate chunk
#define LDS_BYTES (4 * CHUNK_B)  // 65536

typedef __attribute__((ext_vector_type(8))) short short8;
typedef __attribute__((ext_vector_type(4))) float f32x4;

typedef const __attribute__((address_space(1))) unsigned int g_u32;
typedef __attribute__((address_space(3))) unsigned int l_u32;

__device__ __forceinline__ unsigned short f2bf(float f) {
    union { float f; unsigned int u; } cv; cv.f = f;
    unsigned int u = cv.u + 0x7FFFu + ((cv.u >> 16) & 1u);
    return (unsigned short)(u >> 16);
}

__device__ __forceinline__ void gload_lds16(const void* g, void* l) {
    __builtin_amdgcn_global_load_lds((g_u32*)g, (l_u32*)l, 16, 0, 0);
}

// ---------------------------------------------------------------------------
// k0: rewrite Wq/Wk into frag-major bf16 layout, 16 chunks x 16KB, plus the
// gate chunk (index 16): first 8KB = gate frags (col0=w_vol, col1=w_volu),
// second 8KB zero. ds_read_b128 of a frag = base + lane*16.
// ---------------------------------------------------------------------------
__global__ void k0_prep(const float* __restrict__ Wq, const float* __restrict__ Wk,
                        const float* __restrict__ w_vol, const float* __restrict__ w_volu,
                        unsigned char* __restrict__ Wfrag)
{
    const int tid = threadIdx.x;
    const int n   = blockIdx.x * 8 + (tid >> 5);   // 0..255
    const int k8  = tid & 31;                      // 8-elem group of K
    const int ch  = n >> 4;
    const int cc  = n & 15;
    const int ks  = k8 >> 2;
    const int g   = k8 & 3;

    short8 vq, vk;
    #pragma unroll
    for (int e = 0; e < 8; ++e) {
        const int k = k8 * 8 + e;
        vq[e] = (short)f2bf(Wq[(size_t)k * DN + n]);
        vk[e] = (short)f2bf(Wk[(size_t)k * DN + n]);
    }
    const size_t base = (size_t)ch * CHUNK_B + (size_t)((g * 16 + cc) * 16);
    *(short8*)(Wfrag + base + (size_t)(ks)     * 1024) = vq;
    *(short8*)(Wfrag + base + (size_t)(8 + ks) * 1024) = vk;

    unsigned char* Gfrag = Wfrag + (size_t)16 * CHUNK_B;
    if (blockIdx.x < 2) {
        const int gc = blockIdx.x * 8 + (tid >> 5);   // 0..15
        short8 vg;
        #pragma unroll
        for (int e = 0; e < 8; ++e) {
            const int k = k8 * 8 + e;
            float v = (gc == 0) ? w_vol[k] : ((gc == 1) ? w_volu[k] : 0.0f);
            vg[e] = (short)f2bf(v);
        }
        *(short8*)(Gfrag + (size_t)ks * 1024 + (size_t)((g * 16 + gc) * 16)) = vg;
    } else if (blockIdx.x < 4) {
        short8 z = (short8)(0);
        *(short8*)(Gfrag + 8192 + (size_t)(blockIdx.x - 2) * 4096 + (size_t)tid * 16) = z;
    }
}

// ---------------------------------------------------------------------------
// k0b: MFMA version — k-projection (NO bias) at rows s = 31 + 32j, j=0..255
// per batch. One wave per 16 rows: A gathered per-lane from x, B = k-slot
// frags read directly from Wfrag (L2-hot). kpatch[b][j][n], fp32.
// Must run AFTER k0_prep (same stream).
// ---------------------------------------------------------------------------
__global__ void k0b_kpatch(const float* __restrict__ x,
                           const unsigned char* __restrict__ Wfrag,
                           float* __restrict__ kpatch)
{
    const int b   = blockIdx.y;
    const int grp = blockIdx.x;        // 0..15 (16 rows each)
    const int l   = threadIdx.x;       // 0..63
    const int g   = l >> 4;
    const int c   = l & 15;

    // A fragment: lane (g,c) holds row c(local), k = ks*32 + g*8 .. +8
    short8 af[8];
    const int grow = 31 + 32 * (grp * 16 + c);
    const float* xr = x + ((size_t)b * SN + grow) * DN;
    #pragma unroll
    for (int ks = 0; ks < 8; ++ks) {
        const float4 lo = *(const float4*)(xr + ks * 32 + g * 8);
        const float4 hi = *(const float4*)(xr + ks * 32 + g * 8 + 4);
        short8 sv;
        sv[0] = (short)f2bf(lo.x); sv[1] = (short)f2bf(lo.y);
        sv[2] = (short)f2bf(lo.z); sv[3] = (short)f2bf(lo.w);
        sv[4] = (short)f2bf(hi.x); sv[5] = (short)f2bf(hi.y);
        sv[6] = (short)f2bf(hi.z); sv[7] = (short)f2bf(hi.w);
        af[ks] = sv;
    }

    #pragma unroll 2
    for (int chv = 0; chv < 16; ++chv) {
        f32x4 ck = (f32x4)(0.f);
        #pragma unroll
        for (int ks = 0; ks < 8; ++ks) {
            const short8 bkf = *(const short8*)(Wfrag + (size_t)chv * CHUNK_B
                                                + (size_t)(8 + ks) * 1024 + (size_t)l * 16);
            ck = __builtin_amdgcn_mfma_f32_16x16x32_bf16(af[ks], bkf, ck, 0, 0, 0);
        }
        // C layout: col = lane&15, row = (lane>>4)*4 + reg
        #pragma unroll
        for (int r = 0; r < 4; ++r)
            kpatch[((size_t)b * 256 + grp * 16 + g * 4 + r) * DN + chv * 16 + c] = ck[r];
    }
}

// ---------------------------------------------------------------------------
// k1: single A-window MFMA q/k projection; k_{s-1} via accumulator row-shift.
// 512 threads (8 waves), 256 rows/block. Phase 1: x staged in 64-row quarters
// ping-ponging through LDS halves. Phase 2: W streamed 17 chunks through
// 4 x 16KB buffers, counted vmcnt, setprio'd MFMA clusters, 1 barrier/chunk.
// (R7-verbatim — the 87 µs benched kernel. Do not restructure the fold.)
// ---------------------------------------------------------------------------
__global__ __launch_bounds__(512, 4) void k1_mfma(
    const float* __restrict__ x,
    const unsigned char* __restrict__ Wfrag,
    const float* __restrict__ kpatch,
    const float* __restrict__ bq, const float* __restrict__ bk,
    const float* __restrict__ b_vol, const float* __restrict__ b_volu,
    float* __restrict__ bp_out, int* __restrict__ flags)
{
    extern __shared__ unsigned char lds[];           // 65536 B

    const int tid  = threadIdx.x;
    const int wq   = tid >> 6;                       // 0..7
    const int l    = tid & 63;
    const int g    = l >> 4;
    const int c    = l & 15;
    const int b    = blockIdx.y;
    const int blkx = blockIdx.x;
    const int s0   = blkx * MBLK;

    const float* xb = x + (size_t)b * SN * DN;

    // ---- phase 1: quarter j (64 rows, 32KB) lives in LDS half j&1
    short8 a[2][8];
    {
        // stage quarter 0
        {
            unsigned char* reg = lds;
            #pragma unroll
            for (int it = 0; it < 4; ++it) {
                const int f = it * 512 + tid;            // 0..2047
                const int lr = f >> 5, ch = f & 31;      // 64 rows x 32 chunks
                const float4* p = (const float4*)(xb + (size_t)(s0 + lr) * DN + ch * 8);
                const float4 aa = p[0], dd = p[1];
                short8 sv;
                sv[0] = (short)f2bf(aa.x); sv[1] = (short)f2bf(aa.y);
                sv[2] = (short)f2bf(aa.z); sv[3] = (short)f2bf(aa.w);
                sv[4] = (short)f2bf(dd.x); sv[5] = (short)f2bf(dd.y);
                sv[6] = (short)f2bf(dd.z); sv[7] = (short)f2bf(dd.w);
                *(short8*)(reg + lr * 512 + ((ch * 16) ^ ((lr & 7) << 4))) = sv;
            }
        }
        __syncthreads();
        #pragma unroll
        for (int j = 0; j < 4; ++j) {
            if (j < 3) {
                unsigned char* reg = lds + ((j + 1) & 1) * 32768;
                #pragma unroll
                for (int it = 0; it < 4; ++it) {
                    const int f = it * 512 + tid;
                    const int lr = f >> 5, ch = f & 31;
                    const float4* p = (const float4*)(xb + (size_t)(s0 + (j + 1) * 64 + lr) * DN + ch * 8);
                    const float4 aa = p[0], dd = p[1];
                    short8 sv;
                    sv[0] = (short)f2bf(aa.x); sv[1] = (short)f2bf(aa.y);
                    sv[2] = (short)f2bf(aa.z); sv[3] = (short)f2bf(aa.w);
                    sv[4] = (short)f2bf(dd.x); sv[5] = (short)f2bf(dd.y);
                    sv[6] = (short)f2bf(dd.z); sv[7] = (short)f2bf(dd.w);
                    *(short8*)(reg + lr * 512 + ((ch * 16) ^ ((lr & 7) << 4))) = sv;
                }
            }
            if ((wq >> 1) == j) {
                const unsigned char* reg = lds + (j & 1) * 32768;
                #pragma unroll
                for (int m = 0; m < 2; ++m) {
                    const int lr = (wq & 1) * 32 + m * 16 + c;
                    #pragma unroll
                    for (int ks = 0; ks < 8; ++ks)
                        a[m][ks] = *(const short8*)(reg + lr * 512 + (((ks * 64) + g * 16) ^ ((lr & 7) << 4)));
                }
            }
            __syncthreads();
        }
    }

    // ---- phase 2 prologue: stage chunks 0,1,2 (2 loads/thread each)
    #pragma unroll
    for (int ch = 0; ch < 3; ++ch)
        #pragma unroll
        for (int jj = 0; jj < 2; ++jj)
            gload_lds16(Wfrag + (size_t)ch * CHUNK_B + jj * 8192 + tid * 16,
                        lds + ch * CHUNK_B + jj * 8192 + wq * 1024);
    asm volatile("s_waitcnt vmcnt(4)" ::: "memory");   // chunk 0 resident
    __builtin_amdgcn_s_barrier();

    float dt[2][4], nqv[2][4], nkv[2][4];
    #pragma unroll
    for (int m = 0; m < 2; ++m)
        #pragma unroll
        for (int r = 0; r < 4; ++r) { dt[m][r] = 0.f; nqv[m][r] = 0.f; nkv[m][r] = 0.f; }
    f32x4 cg0 = (f32x4)(0.f), cg1 = (f32x4)(0.f);

    int kpidx = 8 * blkx + wq - 1;
    if (kpidx < 0) kpidx = 0;                        // block0/wave0: value unused (s==0)
    const float* kpp = kpatch + ((size_t)b * 256 + kpidx) * DN;

    // ---- main loop: 17 chunks, 4-buffer, counted vmcnt, 1 barrier/chunk
    #pragma unroll
    for (int i = 0; i < NCHUNK; ++i) {
        if (i + 3 < NCHUNK) {
            #pragma unroll
            for (int jj = 0; jj < 2; ++jj)
                gload_lds16(Wfrag + (size_t)(i + 3) * CHUNK_B + jj * 8192 + tid * 16,
                            lds + ((i + 3) & 3) * CHUNK_B + jj * 8192 + wq * 1024);
        }
        const unsigned char* bb = lds + (i & 3) * CHUNK_B;

        if (i < 16) {
            f32x4 cq0 = (f32x4)(0.f), cq1 = (f32x4)(0.f);
            f32x4 ck0 = (f32x4)(0.f), ck1 = (f32x4)(0.f);
            __builtin_amdgcn_s_setprio(1);
            #pragma unroll
            for (int ks = 0; ks < 8; ++ks) {
                const short8 bqf = *(const short8*)(bb + ks * 1024 + l * 16);
                const short8 bkf = *(const short8*)(bb + (8 + ks) * 1024 + l * 16);
                cq0 = __builtin_amdgcn_mfma_f32_16x16x32_bf16(a[0][ks], bqf, cq0, 0, 0, 0);
                cq1 = __builtin_amdgcn_mfma_f32_16x16x32_bf16(a[1][ks], bqf, cq1, 0, 0, 0);
                ck0 = __builtin_amdgcn_mfma_f32_16x16x32_bf16(a[0][ks], bkf, ck0, 0, 0, 0);
                ck1 = __builtin_amdgcn_mfma_f32_16x16x32_bf16(a[1][ks], bkf, ck1, 0, 0, 0);
            }
            __builtin_amdgcn_s_setprio(0);
            const float bqc = bq[i * 16 + c];
            const float bkc = bk[i * 16 + c];
            const float kb  = kpp[i * 16 + c];
            // k row-shift: row t needs k[t-1]
            const float sh0 = __shfl(ck0[3], (l - 16) & 63);   // (g-1, r=3) -> (g, r=0)
            const float sh1 = __shfl(ck1[3], (l - 16) & 63);
            const float cr  = __shfl(ck0[3], 48 + c);          // m0 row15 -> m1 g0 r0
            const float km00 = (g == 0) ? kb : sh0;
            const float km10 = (g == 0) ? cr : sh1;
            const float kv0[4] = {km00, ck0[0], ck0[1], ck0[2]};
            const float kv1[4] = {km10, ck1[0], ck1[1], ck1[2]};
            #pragma unroll
            for (int r = 0; r < 4; ++r) {
                float qv = cq0[r] + bqc;
                float kv = kv0[r] + bkc;
                dt[0][r]  = fmaf(qv, kv, dt[0][r]);
                nqv[0][r] = fmaf(qv, qv, nqv[0][r]);
                nkv[0][r] = fmaf(kv, kv, nkv[0][r]);
                qv = cq1[r] + bqc;
                kv = kv1[r] + bkc;
                dt[1][r]  = fmaf(qv, kv, dt[1][r]);
                nqv[1][r] = fmaf(qv, qv, nqv[1][r]);
                nkv[1][r] = fmaf(kv, kv, nkv[1][r]);
            }
        } else {
            // gate chunk: q-slot frags only (col0=w_vol, col1=w_volu)
            __builtin_amdgcn_s_setprio(1);
            #pragma unroll
            for (int ks = 0; ks < 8; ++ks) {
                const short8 bgf = *(const short8*)(bb + ks * 1024 + l * 16);
                cg0 = __builtin_amdgcn_mfma_f32_16x16x32_bf16(a[0][ks], bgf, cg0, 0, 0, 0);
                cg1 = __builtin_amdgcn_mfma_f32_16x16x32_bf16(a[1][ks], bgf, cg1, 0, 0, 0);
            }
            __builtin_amdgcn_s_setprio(0);
        }

        if (i + 3 < NCHUNK)      asm volatile("s_waitcnt vmcnt(4)" ::: "memory");
        else if (i + 2 < NCHUNK) asm volatile("s_waitcnt vmcnt(2)" ::: "memory");
        else if (i + 1 < NCHUNK) asm volatile("s_waitcnt vmcnt(0)" ::: "memory");
        __builtin_amdgcn_s_barrier();
    }

    // ---- reduce over the 16 col-lanes of each group
    #pragma unroll
    for (int m = 0; m < 2; ++m)
        #pragma unroll
        for (int r = 0; r < 4; ++r) {
            float aa = dt[m][r], e = nqv[m][r], f = nkv[m][r];
            #pragma unroll
            for (int mask = 1; mask < 16; mask <<= 1) {
                aa += __shfl_xor(aa, mask);
                e  += __shfl_xor(e, mask);
                f  += __shfl_xor(f, mask);
            }
            dt[m][r] = aa; nqv[m][r] = e; nkv[m][r] = f;
        }
    float vu0[4], vu1[4];
    #pragma unroll
    for (int r = 0; r < 4; ++r) { vu0[r] = __shfl_xor(cg0[r], 1); vu1[r] = __shfl_xor(cg1[r], 1); }

    if (c == 0) {
        const float bv = b_vol[0], bu = b_volu[0];
        #pragma unroll
        for (int m = 0; m < 2; ++m)
            #pragma unroll
            for (int r = 0; r < 4; ++r) {
                const int s = s0 + wq * 32 + m * 16 + g * 4 + r;
                const float cgv = (m == 0) ? cg0[r] : cg1[r];
                const float vuv = (m == 0) ? vu0[r] : vu1[r];
                float comb;
                if (s == 0) comb = 1.0f;
                else {
                    float denom = fmaxf(sqrtf(nqv[m][r]), EPSF) * fmaxf(sqrtf(nkv[m][r]), EPSF);
                    float sim   = dt[m][r] / denom;
                    float vol   = 1.f / (1.f + expf(-(cgv + bv)));
                    float volu  = 1.f / (1.f + expf(-(vuv + bu)));
                    comb = (1.f - sim) + 0.3f * vol + 0.2f * volu;
                }
                const float pbp = 1.f / (1.f + expf(-comb));
                const size_t o = (size_t)b * SN + s;
                bp_out[o] = pbp;
                flags[o]  = (pbp > 0.5f) ? 1 : 0;
            }
    }
}

// ---------------------------------------------------------------------------
// k2: per-batch scan of hard flags -> packed dest index, count, boundary sum
// ---------------------------------------------------------------------------
__global__ void k2_scan(const int* __restrict__ flags,
                        const float* __restrict__ bp,
                        int* __restrict__ pidx,
                        int* __restrict__ cnt,
                        float* __restrict__ bsum)
{
    const int b = blockIdx.x;
    const int t = threadIdx.x;
    __shared__ int   ssum[256];
    __shared__ float sf[256];

    const size_t base = (size_t)b * SN + (size_t)t * 32;
    int f[32];
    int run = 0;
    float fs = 0.f;
    #pragma unroll
    for (int i = 0; i < 32; ++i) {
        f[i] = flags[base + i];
        run += f[i];
        float p  = bp[base + i];
        float hf = (float)f[i];
        fs += hf + p - p;
    }
    ssum[t] = run;
    sf[t]   = fs;
    __syncthreads();

    for (int off = 1; off < 256; off <<= 1) {
        int v = (t >= off) ? ssum[t - off] : 0;
        __syncthreads();
        ssum[t] += v;
        __syncthreads();
    }
    const int incl = ssum[t];
    int running = incl - run;
    #pragma unroll
    for (int i = 0; i < 32; ++i) {
        running += f[i];
        pidx[base + i] = f[i] ? (running - 1) : -1;
    }
    if (t == 255) cnt[b] = incl;

    for (int off = 128; off > 0; off >>= 1) {
        if (t < off) sf[t] += sf[t + off];
        __syncthreads();
    }
    if (t == 0) bsum[b] = sf[0];
}

// ---------------------------------------------------------------------------
// k3: gather-copy hard rows; 4 rows per 256-thread block
// ---------------------------------------------------------------------------
__global__ void k3_scatter(const float* __restrict__ x,
                           const int* __restrict__ pidx,
                           float* __restrict__ out_comp)
{
    const int row  = blockIdx.x * 4 + (threadIdx.x >> 6);
    const int lane = threadIdx.x & 63;
    const int p = pidx[row];
    if (p < 0) return;
    const int b = row >> 13;
    const float4* src = (const float4*)(x + (size_t)row * DN);
    float4* dst = (float4*)(out_comp + ((size_t)b * SN + p) * DN);
    dst[lane] = src[lane];
}

// k3b: zero destination rows beyond each batch's boundary count
__global__ void k3b_zerotail(float* __restrict__ out_comp,
                             const int* __restrict__ cnt)
{
    const int gid = blockIdx.x * blockDim.x + threadIdx.x;
    const int b = gid >> 13;
    const int j = gid & (SN - 1);
    if (j >= cnt[b]) {
        float4* dst = (float4*)(out_comp + ((size_t)b * SN + j) * DN);
        const float4 z = make_float4(0.f, 0.f, 0.f, 0.f);
        for (int i = 0; i < DN / 4; ++i) dst[i] = z;
    }
}

// k4: ratio loss
__global__ void k4_loss(const float* __restrict__ bsum, float* __restrict__ out_rl)
{
    if (threadIdx.x == 0) {
        float acc = 0.f;
        for (int i = 0; i < BN; ++i) acc += bsum[i];
        float mean = acc / (float)BN;
        float d = mean - (float)(SN / 4);
        out_rl[0] = d * d;
    }
}

extern "C" void kernel_launch(void* const* d_in, const int* in_sizes, int n_in,
                              void* d_out, int out_size, void* d_ws, size_t ws_size,
                              hipStream_t stream) {
    const float* x      = (const float*)d_in[0];
    const float* Wq     = (const float*)d_in[1];
    const float* bq     = (const float*)d_in[2];
    const float* Wk     = (const float*)d_in[3];
    const float* bk     = (const float*)d_in[4];
    const float* w_vol  = (const float*)d_in[5];
    const float* b_vol  = (const float*)d_in[6];
    const float* w_volu = (const float*)d_in[7];
    const float* b_volu = (const float*)d_in[8];

    float* out_comp = (float*)d_out;                       // B*S*D
    float* out_bp   = out_comp + (size_t)BN * SN * DN;     // B*S
    float* out_rl   = out_bp + (size_t)BN * SN;            // 1

    int*   flags = (int*)d_ws;                             // B*S
    int*   pidx  = flags + (size_t)BN * SN;                // B*S
    int*   cnt   = pidx + (size_t)BN * SN;                 // B
    float* bsum  = (float*)(cnt + BN);                     // B
    unsigned char* Wfrag = (unsigned char*)(bsum + BN);    // 17*16384 = 278528 B
    float* kpatch = (float*)(Wfrag + (size_t)NCHUNK * CHUNK_B); // 16*256*256 f32 = 4 MB

    k0_prep<<<32, 256, 0, stream>>>(Wq, Wk, w_vol, w_volu, Wfrag);

    // depends on Wfrag (same stream -> ordered after k0_prep)
    k0b_kpatch<<<dim3(16, BN), 64, 0, stream>>>(x, Wfrag, kpatch);

    hipFuncSetAttribute((const void*)k1_mfma,
                        hipFuncAttributeMaxDynamicSharedMemorySize, LDS_BYTES);

    k1_mfma<<<dim3(SN / MBLK, BN), 512, LDS_BYTES, stream>>>(
        x, Wfrag, kpatch, bq, bk, b_vol, b_volu, out_bp, flags);

    k2_scan<<<BN, 256, 0, stream>>>(flags, out_bp, pidx, cnt, bsum);

    k3_scatter<<<(BN * SN) / 4, 256, 0, stream>>>(x, pidx, out_comp);

    k3b_zerotail<<<(BN * SN) / 256, 256, 0, stream>>>(out_comp, cnt);

    k4_loss<<<1, 64, 0, stream>>>(bsum, out_rl);
}

// Round 11
// 122.734 us; speedup vs baseline: 3.0413x; 1.1893x over previous
//
#include <hip/hip_runtime.h>
#include <math.h>

#define BN 16
#define SN 8192
#define DN 256
#define MBLK 256
#define EPSF 1e-8f

#define CHUNK_B 16384            // one W chunk: 16 cols x (q,k) frag-major
#define NCHUNK 17                // 16 W chunks + 1 gate chunk
#define LDS_BYTES (4 * CHUNK_B)  // 65536

typedef __attribute__((ext_vector_type(8))) short short8;
typedef __attribute__((ext_vector_type(4))) float f32x4;

typedef const __attribute__((address_space(1))) unsigned int g_u32;
typedef __attribute__((address_space(3))) unsigned int l_u32;

__device__ __forceinline__ unsigned short f2bf(float f) {
    union { float f; unsigned int u; } cv; cv.f = f;
    unsigned int u = cv.u + 0x7FFFu + ((cv.u >> 16) & 1u);
    return (unsigned short)(u >> 16);
}

__device__ __forceinline__ void gload_lds16(const void* g, void* l) {
    __builtin_amdgcn_global_load_lds((g_u32*)g, (l_u32*)l, 16, 0, 0);
}

// ---------------------------------------------------------------------------
// k0: rewrite Wq/Wk into frag-major bf16 layout, 16 chunks x 16KB, plus the
// gate chunk (index 16): first 8KB = gate frags (col0=w_vol, col1=w_volu),
// second 8KB zero. ds_read_b128 of a frag = base + lane*16.
// ---------------------------------------------------------------------------
__global__ void k0_prep(const float* __restrict__ Wq, const float* __restrict__ Wk,
                        const float* __restrict__ w_vol, const float* __restrict__ w_volu,
                        unsigned char* __restrict__ Wfrag)
{
    const int tid = threadIdx.x;
    const int n   = blockIdx.x * 8 + (tid >> 5);   // 0..255
    const int k8  = tid & 31;                      // 8-elem group of K
    const int ch  = n >> 4;
    const int cc  = n & 15;
    const int ks  = k8 >> 2;
    const int g   = k8 & 3;

    short8 vq, vk;
    #pragma unroll
    for (int e = 0; e < 8; ++e) {
        const int k = k8 * 8 + e;
        vq[e] = (short)f2bf(Wq[(size_t)k * DN + n]);
        vk[e] = (short)f2bf(Wk[(size_t)k * DN + n]);
    }
    const size_t base = (size_t)ch * CHUNK_B + (size_t)((g * 16 + cc) * 16);
    *(short8*)(Wfrag + base + (size_t)(ks)     * 1024) = vq;
    *(short8*)(Wfrag + base + (size_t)(8 + ks) * 1024) = vk;

    unsigned char* Gfrag = Wfrag + (size_t)16 * CHUNK_B;
    if (blockIdx.x < 2) {
        const int gc = blockIdx.x * 8 + (tid >> 5);   // 0..15
        short8 vg;
        #pragma unroll
        for (int e = 0; e < 8; ++e) {
            const int k = k8 * 8 + e;
            float v = (gc == 0) ? w_vol[k] : ((gc == 1) ? w_volu[k] : 0.0f);
            vg[e] = (short)f2bf(v);
        }
        *(short8*)(Gfrag + (size_t)ks * 1024 + (size_t)((g * 16 + gc) * 16)) = vg;
    } else if (blockIdx.x < 4) {
        short8 z = (short8)(0);
        *(short8*)(Gfrag + 8192 + (size_t)(blockIdx.x - 2) * 4096 + (size_t)tid * 16) = z;
    }
}

// ---------------------------------------------------------------------------
// k0b: MFMA k-projection (NO bias) at rows s = 31 + 32j, j=0..255 per batch.
// Grid (64, BN) x 256 threads: grp = bx>>2 (16 rows), wave wq handles
// chv = (bx&3)*4 + wq. 4096 waves total = 16/CU -> latency hidden by TLP.
// A gathered per-lane from x; B = k-slot frags from Wfrag (L2/L3-hot).
// Must run AFTER k0_prep (same stream).
// ---------------------------------------------------------------------------
__global__ __launch_bounds__(256) void k0b_kpatch(
    const float* __restrict__ x,
    const unsigned char* __restrict__ Wfrag,
    float* __restrict__ kpatch)
{
    const int b   = blockIdx.y;
    const int grp = blockIdx.x >> 2;               // 0..15 (16 rows each)
    const int sub = blockIdx.x & 3;
    const int wq  = threadIdx.x >> 6;              // 0..3
    const int l   = threadIdx.x & 63;
    const int g   = l >> 4;
    const int c   = l & 15;
    const int chv = sub * 4 + wq;                  // 0..15

    // A fragment: lane (g,c) holds row c(local), k = ks*32 + g*8 .. +8
    short8 af[8];
    const int grow = 31 + 32 * (grp * 16 + c);
    const float* xr = x + ((size_t)b * SN + grow) * DN;
    #pragma unroll
    for (int ks = 0; ks < 8; ++ks) {
        const float4 lo = *(const float4*)(xr + ks * 32 + g * 8);
        const float4 hi = *(const float4*)(xr + ks * 32 + g * 8 + 4);
        short8 sv;
        sv[0] = (short)f2bf(lo.x); sv[1] = (short)f2bf(lo.y);
        sv[2] = (short)f2bf(lo.z); sv[3] = (short)f2bf(lo.w);
        sv[4] = (short)f2bf(hi.x); sv[5] = (short)f2bf(hi.y);
        sv[6] = (short)f2bf(hi.z); sv[7] = (short)f2bf(hi.w);
        af[ks] = sv;
    }

    f32x4 ck = (f32x4)(0.f);
    #pragma unroll
    for (int ks = 0; ks < 8; ++ks) {
        const short8 bkf = *(const short8*)(Wfrag + (size_t)chv * CHUNK_B
                                            + (size_t)(8 + ks) * 1024 + (size_t)l * 16);
        ck = __builtin_amdgcn_mfma_f32_16x16x32_bf16(af[ks], bkf, ck, 0, 0, 0);
    }
    // C layout: col = lane&15, row = (lane>>4)*4 + reg
    #pragma unroll
    for (int r = 0; r < 4; ++r)
        kpatch[((size_t)b * 256 + grp * 16 + g * 4 + r) * DN + chv * 16 + c] = ck[r];
}

// ---------------------------------------------------------------------------
// k1: single A-window MFMA q/k projection; k_{s-1} via accumulator row-shift.
// 512 threads (8 waves), 256 rows/block. Phase 1: x staged in 64-row quarters
// ping-ponging through LDS halves. Phase 2: W streamed 17 chunks through
// 4 x 16KB buffers, counted vmcnt, setprio'd MFMA clusters, 1 barrier/chunk.
// (R7-verbatim — the 87 µs benched kernel. Do not restructure the fold.)
// ---------------------------------------------------------------------------
__global__ __launch_bounds__(512, 4) void k1_mfma(
    const float* __restrict__ x,
    const unsigned char* __restrict__ Wfrag,
    const float* __restrict__ kpatch,
    const float* __restrict__ bq, const float* __restrict__ bk,
    const float* __restrict__ b_vol, const float* __restrict__ b_volu,
    float* __restrict__ bp_out, int* __restrict__ flags)
{
    extern __shared__ unsigned char lds[];           // 65536 B

    const int tid  = threadIdx.x;
    const int wq   = tid >> 6;                       // 0..7
    const int l    = tid & 63;
    const int g    = l >> 4;
    const int c    = l & 15;
    const int b    = blockIdx.y;
    const int blkx = blockIdx.x;
    const int s0   = blkx * MBLK;

    const float* xb = x + (size_t)b * SN * DN;

    // ---- phase 1: quarter j (64 rows, 32KB) lives in LDS half j&1
    short8 a[2][8];
    {
        // stage quarter 0
        {
            unsigned char* reg = lds;
            #pragma unroll
            for (int it = 0; it < 4; ++it) {
                const int f = it * 512 + tid;            // 0..2047
                const int lr = f >> 5, ch = f & 31;      // 64 rows x 32 chunks
                const float4* p = (const float4*)(xb + (size_t)(s0 + lr) * DN + ch * 8);
                const float4 aa = p[0], dd = p[1];
                short8 sv;
                sv[0] = (short)f2bf(aa.x); sv[1] = (short)f2bf(aa.y);
                sv[2] = (short)f2bf(aa.z); sv[3] = (short)f2bf(aa.w);
                sv[4] = (short)f2bf(dd.x); sv[5] = (short)f2bf(dd.y);
                sv[6] = (short)f2bf(dd.z); sv[7] = (short)f2bf(dd.w);
                *(short8*)(reg + lr * 512 + ((ch * 16) ^ ((lr & 7) << 4))) = sv;
            }
        }
        __syncthreads();
        #pragma unroll
        for (int j = 0; j < 4; ++j) {
            if (j < 3) {
                unsigned char* reg = lds + ((j + 1) & 1) * 32768;
                #pragma unroll
                for (int it = 0; it < 4; ++it) {
                    const int f = it * 512 + tid;
                    const int lr = f >> 5, ch = f & 31;
                    const float4* p = (const float4*)(xb + (size_t)(s0 + (j + 1) * 64 + lr) * DN + ch * 8);
                    const float4 aa = p[0], dd = p[1];
                    short8 sv;
                    sv[0] = (short)f2bf(aa.x); sv[1] = (short)f2bf(aa.y);
                    sv[2] = (short)f2bf(aa.z); sv[3] = (short)f2bf(aa.w);
                    sv[4] = (short)f2bf(dd.x); sv[5] = (short)f2bf(dd.y);
                    sv[6] = (short)f2bf(dd.z); sv[7] = (short)f2bf(dd.w);
                    *(short8*)(reg + lr * 512 + ((ch * 16) ^ ((lr & 7) << 4))) = sv;
                }
            }
            if ((wq >> 1) == j) {
                const unsigned char* reg = lds + (j & 1) * 32768;
                #pragma unroll
                for (int m = 0; m < 2; ++m) {
                    const int lr = (wq & 1) * 32 + m * 16 + c;
                    #pragma unroll
                    for (int ks = 0; ks < 8; ++ks)
                        a[m][ks] = *(const short8*)(reg + lr * 512 + (((ks * 64) + g * 16) ^ ((lr & 7) << 4)));
                }
            }
            __syncthreads();
        }
    }

    // ---- phase 2 prologue: stage chunks 0,1,2 (2 loads/thread each)
    #pragma unroll
    for (int ch = 0; ch < 3; ++ch)
        #pragma unroll
        for (int jj = 0; jj < 2; ++jj)
            gload_lds16(Wfrag + (size_t)ch * CHUNK_B + jj * 8192 + tid * 16,
                        lds + ch * CHUNK_B + jj * 8192 + wq * 1024);
    asm volatile("s_waitcnt vmcnt(4)" ::: "memory");   // chunk 0 resident
    __builtin_amdgcn_s_barrier();

    float dt[2][4], nqv[2][4], nkv[2][4];
    #pragma unroll
    for (int m = 0; m < 2; ++m)
        #pragma unroll
        for (int r = 0; r < 4; ++r) { dt[m][r] = 0.f; nqv[m][r] = 0.f; nkv[m][r] = 0.f; }
    f32x4 cg0 = (f32x4)(0.f), cg1 = (f32x4)(0.f);

    int kpidx = 8 * blkx + wq - 1;
    if (kpidx < 0) kpidx = 0;                        // block0/wave0: value unused (s==0)
    const float* kpp = kpatch + ((size_t)b * 256 + kpidx) * DN;

    // ---- main loop: 17 chunks, 4-buffer, counted vmcnt, 1 barrier/chunk
    #pragma unroll
    for (int i = 0; i < NCHUNK; ++i) {
        if (i + 3 < NCHUNK) {
            #pragma unroll
            for (int jj = 0; jj < 2; ++jj)
                gload_lds16(Wfrag + (size_t)(i + 3) * CHUNK_B + jj * 8192 + tid * 16,
                            lds + ((i + 3) & 3) * CHUNK_B + jj * 8192 + wq * 1024);
        }
        const unsigned char* bb = lds + (i & 3) * CHUNK_B;

        if (i < 16) {
            f32x4 cq0 = (f32x4)(0.f), cq1 = (f32x4)(0.f);
            f32x4 ck0 = (f32x4)(0.f), ck1 = (f32x4)(0.f);
            __builtin_amdgcn_s_setprio(1);
            #pragma unroll
            for (int ks = 0; ks < 8; ++ks) {
                const short8 bqf = *(const short8*)(bb + ks * 1024 + l * 16);
                const short8 bkf = *(const short8*)(bb + (8 + ks) * 1024 + l * 16);
                cq0 = __builtin_amdgcn_mfma_f32_16x16x32_bf16(a[0][ks], bqf, cq0, 0, 0, 0);
                cq1 = __builtin_amdgcn_mfma_f32_16x16x32_bf16(a[1][ks], bqf, cq1, 0, 0, 0);
                ck0 = __builtin_amdgcn_mfma_f32_16x16x32_bf16(a[0][ks], bkf, ck0, 0, 0, 0);
                ck1 = __builtin_amdgcn_mfma_f32_16x16x32_bf16(a[1][ks], bkf, ck1, 0, 0, 0);
            }
            __builtin_amdgcn_s_setprio(0);
            const float bqc = bq[i * 16 + c];
            const float bkc = bk[i * 16 + c];
            const float kb  = kpp[i * 16 + c];
            // k row-shift: row t needs k[t-1]
            const float sh0 = __shfl(ck0[3], (l - 16) & 63);   // (g-1, r=3) -> (g, r=0)
            const float sh1 = __shfl(ck1[3], (l - 16) & 63);
            const float cr  = __shfl(ck0[3], 48 + c);          // m0 row15 -> m1 g0 r0
            const float km00 = (g == 0) ? kb : sh0;
            const float km10 = (g == 0) ? cr : sh1;
            const float kv0[4] = {km00, ck0[0], ck0[1], ck0[2]};
            const float kv1[4] = {km10, ck1[0], ck1[1], ck1[2]};
            #pragma unroll
            for (int r = 0; r < 4; ++r) {
                float qv = cq0[r] + bqc;
                float kv = kv0[r] + bkc;
                dt[0][r]  = fmaf(qv, kv, dt[0][r]);
                nqv[0][r] = fmaf(qv, qv, nqv[0][r]);
                nkv[0][r] = fmaf(kv, kv, nkv[0][r]);
                qv = cq1[r] + bqc;
                kv = kv1[r] + bkc;
                dt[1][r]  = fmaf(qv, kv, dt[1][r]);
                nqv[1][r] = fmaf(qv, qv, nqv[1][r]);
                nkv[1][r] = fmaf(kv, kv, nkv[1][r]);
            }
        } else {
            // gate chunk: q-slot frags only (col0=w_vol, col1=w_volu)
            __builtin_amdgcn_s_setprio(1);
            #pragma unroll
            for (int ks = 0; ks < 8; ++ks) {
                const short8 bgf = *(const short8*)(bb + ks * 1024 + l * 16);
                cg0 = __builtin_amdgcn_mfma_f32_16x16x32_bf16(a[0][ks], bgf, cg0, 0, 0, 0);
                cg1 = __builtin_amdgcn_mfma_f32_16x16x32_bf16(a[1][ks], bgf, cg1, 0, 0, 0);
            }
            __builtin_amdgcn_s_setprio(0);
        }

        if (i + 3 < NCHUNK)      asm volatile("s_waitcnt vmcnt(4)" ::: "memory");
        else if (i + 2 < NCHUNK) asm volatile("s_waitcnt vmcnt(2)" ::: "memory");
        else if (i + 1 < NCHUNK) asm volatile("s_waitcnt vmcnt(0)" ::: "memory");
        __builtin_amdgcn_s_barrier();
    }

    // ---- reduce over the 16 col-lanes of each group
    #pragma unroll
    for (int m = 0; m < 2; ++m)
        #pragma unroll
        for (int r = 0; r < 4; ++r) {
            float aa = dt[m][r], e = nqv[m][r], f = nkv[m][r];
            #pragma unroll
            for (int mask = 1; mask < 16; mask <<= 1) {
                aa += __shfl_xor(aa, mask);
                e  += __shfl_xor(e, mask);
                f  += __shfl_xor(f, mask);
            }
            dt[m][r] = aa; nqv[m][r] = e; nkv[m][r] = f;
        }
    float vu0[4], vu1[4];
    #pragma unroll
    for (int r = 0; r < 4; ++r) { vu0[r] = __shfl_xor(cg0[r], 1); vu1[r] = __shfl_xor(cg1[r], 1); }

    if (c == 0) {
        const float bv = b_vol[0], bu = b_volu[0];
        #pragma unroll
        for (int m = 0; m < 2; ++m)
            #pragma unroll
            for (int r = 0; r < 4; ++r) {
                const int s = s0 + wq * 32 + m * 16 + g * 4 + r;
                const float cgv = (m == 0) ? cg0[r] : cg1[r];
                const float vuv = (m == 0) ? vu0[r] : vu1[r];
                float comb;
                if (s == 0) comb = 1.0f;
                else {
                    float denom = fmaxf(sqrtf(nqv[m][r]), EPSF) * fmaxf(sqrtf(nkv[m][r]), EPSF);
                    float sim   = dt[m][r] / denom;
                    float vol   = 1.f / (1.f + expf(-(cgv + bv)));
                    float volu  = 1.f / (1.f + expf(-(vuv + bu)));
                    comb = (1.f - sim) + 0.3f * vol + 0.2f * volu;
                }
                const float pbp = 1.f / (1.f + expf(-comb));
                const size_t o = (size_t)b * SN + s;
                bp_out[o] = pbp;
                flags[o]  = (pbp > 0.5f) ? 1 : 0;
            }
    }
}

// ---------------------------------------------------------------------------
// k2: per-batch scan of hard flags -> packed dest index, count, boundary sum
// ---------------------------------------------------------------------------
__global__ void k2_scan(const int* __restrict__ flags,
                        const float* __restrict__ bp,
                        int* __restrict__ pidx,
                        int* __restrict__ cnt,
                        float* __restrict__ bsum)
{
    const int b = blockIdx.x;
    const int t = threadIdx.x;
    __shared__ int   ssum[256];
    __shared__ float sf[256];

    const size_t base = (size_t)b * SN + (size_t)t * 32;
    int f[32];
    int run = 0;
    float fs = 0.f;
    #pragma unroll
    for (int i = 0; i < 32; ++i) {
        f[i] = flags[base + i];
        run += f[i];
        float p  = bp[base + i];
        float hf = (float)f[i];
        fs += hf + p - p;
    }
    ssum[t] = run;
    sf[t]   = fs;
    __syncthreads();

    for (int off = 1; off < 256; off <<= 1) {
        int v = (t >= off) ? ssum[t - off] : 0;
        __syncthreads();
        ssum[t] += v;
        __syncthreads();
    }
    const int incl = ssum[t];
    int running = incl - run;
    #pragma unroll
    for (int i = 0; i < 32; ++i) {
        running += f[i];
        pidx[base + i] = f[i] ? (running - 1) : -1;
    }
    if (t == 255) cnt[b] = incl;

    for (int off = 128; off > 0; off >>= 1) {
        if (t < off) sf[t] += sf[t + off];
        __syncthreads();
    }
    if (t == 0) bsum[b] = sf[0];
}

// ---------------------------------------------------------------------------
// k3: gather-copy hard rows; 4 rows per 256-thread block
// ---------------------------------------------------------------------------
__global__ void k3_scatter(const float* __restrict__ x,
                           const int* __restrict__ pidx,
                           float* __restrict__ out_comp)
{
    const int row  = blockIdx.x * 4 + (threadIdx.x >> 6);
    const int lane = threadIdx.x & 63;
    const int p = pidx[row];
    if (p < 0) return;
    const int b = row >> 13;
    const float4* src = (const float4*)(x + (size_t)row * DN);
    float4* dst = (float4*)(out_comp + ((size_t)b * SN + p) * DN);
    dst[lane] = src[lane];
}

// k3b: zero destination rows beyond each batch's boundary count
__global__ void k3b_zerotail(float* __restrict__ out_comp,
                             const int* __restrict__ cnt)
{
    const int gid = blockIdx.x * blockDim.x + threadIdx.x;
    const int b = gid >> 13;
    const int j = gid & (SN - 1);
    if (j >= cnt[b]) {
        float4* dst = (float4*)(out_comp + ((size_t)b * SN + j) * DN);
        const float4 z = make_float4(0.f, 0.f, 0.f, 0.f);
        for (int i = 0; i < DN / 4; ++i) dst[i] = z;
    }
}

// k4: ratio loss
__global__ void k4_loss(const float* __restrict__ bsum, float* __restrict__ out_rl)
{
    if (threadIdx.x == 0) {
        float acc = 0.f;
        for (int i = 0; i < BN; ++i) acc += bsum[i];
        float mean = acc / (float)BN;
        float d = mean - (float)(SN / 4);
        out_rl[0] = d * d;
    }
}

extern "C" void kernel_launch(void* const* d_in, const int* in_sizes, int n_in,
                              void* d_out, int out_size, void* d_ws, size_t ws_size,
                              hipStream_t stream) {
    const float* x      = (const float*)d_in[0];
    const float* Wq     = (const float*)d_in[1];
    const float* bq     = (const float*)d_in[2];
    const float* Wk     = (const float*)d_in[3];
    const float* bk     = (const float*)d_in[4];
    const float* w_vol  = (const float*)d_in[5];
    const float* b_vol  = (const float*)d_in[6];
    const float* w_volu = (const float*)d_in[7];
    const float* b_volu = (const float*)d_in[8];

    float* out_comp = (float*)d_out;                       // B*S*D
    float* out_bp   = out_comp + (size_t)BN * SN * DN;     // B*S
    float* out_rl   = out_bp + (size_t)BN * SN;            // 1

    int*   flags = (int*)d_ws;                             // B*S
    int*   pidx  = flags + (size_t)BN * SN;                // B*S
    int*   cnt   = pidx + (size_t)BN * SN;                 // B
    float* bsum  = (float*)(cnt + BN);                     // B
    unsigned char* Wfrag = (unsigned char*)(bsum + BN);    // 17*16384 = 278528 B
    float* kpatch = (float*)(Wfrag + (size_t)NCHUNK * CHUNK_B); // 16*256*256 f32 = 4 MB

    k0_prep<<<32, 256, 0, stream>>>(Wq, Wk, w_vol, w_volu, Wfrag);

    // depends on Wfrag (same stream -> ordered after k0_prep)
    k0b_kpatch<<<dim3(64, BN), 256, 0, stream>>>(x, Wfrag, kpatch);

    hipFuncSetAttribute((const void*)k1_mfma,
                        hipFuncAttributeMaxDynamicSharedMemorySize, LDS_BYTES);

    k1_mfma<<<dim3(SN / MBLK, BN), 512, LDS_BYTES, stream>>>(
        x, Wfrag, kpatch, bq, bk, b_vol, b_volu, out_bp, flags);

    k2_scan<<<BN, 256, 0, stream>>>(flags, out_bp, pidx, cnt, bsum);

    k3_scatter<<<(BN * SN) / 4, 256, 0, stream>>>(x, pidx, out_comp);

    k3b_zerotail<<<(BN * SN) / 256, 256, 0, stream>>>(out_comp, cnt);

    k4_loss<<<1, 64, 0, stream>>>(bsum, out_rl);
}